// Round 1
// baseline (119.946 us; speedup 1.0000x reference)
//
#include <hip/hip_runtime.h>
#include <math.h>

#define BB 32
#define LL 1024
#define CC 1024
#define EE 64
#define TASKS 8

__device__ __forceinline__ float gelu_exact(float x) {
    // gelu(x) = 0.5*x*(1+erf(x/sqrt(2))), approximate=False
    return 0.5f * x * (1.0f + erff(x * 0.7071067811865476f));
}

// One block per batch row: hgate -> logits -> softmax -> top-2 -> P_t
__global__ void gate_kernel(const float* __restrict__ x2,   // (B,8)
                            const float* __restrict__ W1,   // (8,1024)
                            const float* __restrict__ b1,   // (1024)
                            const float* __restrict__ W2,   // (1024,128)
                            float* __restrict__ Pt,         // (B,E) ws
                            float* __restrict__ gate_g,     // (B,2) ws
                            int*   __restrict__ gate_i)     // (B,2) ws
{
    const int b = blockIdx.x;
    const int tid = threadIdx.x;
    __shared__ float hg[CC];
    __shared__ float lg[EE];

    float xv[TASKS];
#pragma unroll
    for (int t = 0; t < TASKS; ++t) xv[t] = x2[b * TASKS + t];

    // hgate = gelu(x2 @ W1 + b1)
    for (int c = tid; c < CC; c += blockDim.x) {
        float acc = b1[c];
#pragma unroll
        for (int t = 0; t < TASKS; ++t) acc += xv[t] * W1[t * CC + c];
        hg[c] = gelu_exact(acc);
    }
    __syncthreads();

    // logits[e] = sum_c hg[c] * W2[c,e], e in [0,64); 4 threads per expert
    {
        const int e = tid >> 2;
        const int sub = tid & 3;
        float acc = 0.f;
        for (int c = sub; c < CC; c += 4) acc += hg[c] * W2[c * 128 + e];
        acc += __shfl_xor(acc, 1);
        acc += __shfl_xor(acc, 2);
        if (sub == 0) lg[e] = acc;
    }
    __syncthreads();

    // wave 0 (64 lanes == 64 experts): softmax + top-2 with lowest-index ties
    if (tid < EE) {
        const int lane = tid;
        float v = lg[lane];
        float m = v;
#pragma unroll
        for (int off = 32; off; off >>= 1) m = fmaxf(m, __shfl_xor(m, off));
        float ex = expf(v - m);
        float sum = ex;
#pragma unroll
        for (int off = 32; off; off >>= 1) sum += __shfl_xor(sum, off);
        float p = ex / sum + 1e-4f;

        // argmax #1 (ties -> lowest index, matching lax.top_k)
        float bv = p; int bi = lane;
#pragma unroll
        for (int off = 32; off; off >>= 1) {
            float ov = __shfl_xor(bv, off);
            int   oi = __shfl_xor(bi, off);
            if (ov > bv || (ov == bv && oi < bi)) { bv = ov; bi = oi; }
        }
        // argmax #2 (exclude winner lane; p > 0 so -1 acts as -inf)
        float p2 = (lane == bi) ? -1.f : p;
        float bv2 = p2; int bi2 = lane;
#pragma unroll
        for (int off = 32; off; off >>= 1) {
            float ov = __shfl_xor(bv2, off);
            int   oi = __shfl_xor(bi2, off);
            if (ov > bv2 || (ov == bv2 && oi < bi2)) { bv2 = ov; bi2 = oi; }
        }
        const float thresh = bv2;
        Pt[b * EE + lane] = (p >= thresh) ? p : 0.f;
        if (lane == 0) {
            gate_g[b * 2 + 0] = bv;
            gate_g[b * 2 + 1] = bv2;
            gate_i[b * 2 + 0] = bi;
            gate_i[b * 2 + 1] = bi2;
        }
    }
}

// Per-batch row scale s[b,l] and un-gated token-mask partial tm[b,l]
__global__ void srow_kernel(const float* __restrict__ G,      // (B,E,L)
                            const float* __restrict__ gate_g, // (B,2)
                            const int*   __restrict__ gate_i, // (B,2)
                            float* __restrict__ s,            // (B,L) ws
                            float* __restrict__ tm)           // (B,L) ws
{
    const int b = blockIdx.x;
    const float g1 = gate_g[b * 2 + 0];
    const float g2 = gate_g[b * 2 + 1];
    const int i1 = gate_i[b * 2 + 0];
    const int i2 = gate_i[b * 2 + 1];
    const float* G1 = G + ((size_t)b * EE + i1) * LL;
    const float* G2 = G + ((size_t)b * EE + i2) * LL;
    for (int l = threadIdx.x; l < LL; l += blockDim.x) {
        float a = G1[l];
        float c = G2[l];
        s[b * LL + l]  = g1 * a + g2 * c;
        tm[b * LL + l] = a + c;
    }
}

// Deterministic reductions: expert_mask (64) and token_mask (1024)
__global__ void reduce_kernel(const float* __restrict__ Pt,  // (B,E)
                              const float* __restrict__ tm,  // (B,L)
                              float* __restrict__ expert_mask,
                              float* __restrict__ token_mask)
{
    const int tid = threadIdx.x;
    if (tid < EE) {
        float acc = 0.f;
        for (int b = 0; b < BB; ++b) acc += Pt[b * EE + tid];
        expert_mask[tid] = acc;
    }
    {
        float acc = 0.f;
        for (int b = 0; b < BB; ++b) acc += tm[b * LL + tid];
        token_mask[tid] = acc;
    }
}

// y[b,l,c] = x[b,l,c] * s[b,l] — the 256 MB streaming kernel
__global__ void scale_kernel(const float4* __restrict__ x,
                             const float*  __restrict__ s,
                             float4* __restrict__ y, int n4)
{
    int i = blockIdx.x * blockDim.x + threadIdx.x;
    const int stride = gridDim.x * blockDim.x;
    for (; i < n4; i += stride) {
        const float sv = __ldg(&s[i >> 8]);   // 256 float4 per (b,l) row
        float4 v = x[i];
        v.x *= sv; v.y *= sv; v.z *= sv; v.w *= sv;
        y[i] = v;
    }
}

extern "C" void kernel_launch(void* const* d_in, const int* in_sizes, int n_in,
                              void* d_out, int out_size, void* d_ws, size_t ws_size,
                              hipStream_t stream) {
    const float* x  = (const float*)d_in[0];  // (32,1024,1024)
    const float* x2 = (const float*)d_in[1];  // (32,8)
    const float* G  = (const float*)d_in[2];  // (32,64,1024)
    const float* W1 = (const float*)d_in[3];  // (8,1024)
    const float* b1 = (const float*)d_in[4];  // (1024)
    const float* W2 = (const float*)d_in[5];  // (1024,128)
    // d_in[6] = k (==2, hardcoded)

    float* y           = (float*)d_out;                  // (32,1024,1024)
    float* expert_mask = y + (size_t)BB * LL * CC;       // (1,64)
    float* token_mask  = expert_mask + EE;               // (1,1024)

    float* s      = (float*)d_ws;        // B*L
    float* tm     = s + BB * LL;         // B*L
    float* Pt     = tm + BB * LL;        // B*E
    float* gate_g = Pt + BB * EE;        // B*2
    int*   gate_i = (int*)(gate_g + BB * 2); // B*2

    gate_kernel<<<BB, 256, 0, stream>>>(x2, W1, b1, W2, Pt, gate_g, gate_i);
    srow_kernel<<<BB, 256, 0, stream>>>(G, gate_g, gate_i, s, tm);
    reduce_kernel<<<1, 1024, 0, stream>>>(Pt, tm, expert_mask, token_mask);

    const int n4 = BB * LL * CC / 4;
    scale_kernel<<<2048, 256, 0, stream>>>((const float4*)x, s, (float4*)y, n4);
}

// Round 2
// 59.198 us; speedup vs baseline: 2.0262x; 2.0262x over previous
//
#include <hip/hip_runtime.h>
#include <math.h>

#define BB 32
#define LL 1024
#define CC 1024
#define EE 64
#define TASKS 8

__device__ __forceinline__ float gelu_exact(float x) {
    // gelu(x) = 0.5*x*(1+erf(x/sqrt(2))), approximate=False
    return 0.5f * x * (1.0f + erff(x * 0.7071067811865476f));
}

// One block (1024 threads) per batch row:
// hgate -> logits (coalesced, wave-parallel) -> softmax -> top-2 -> P_t
// -> fused s/tm row computation (was srow_kernel).
__global__ void __launch_bounds__(1024)
gate_kernel(const float* __restrict__ x2,   // (B,8)
            const float* __restrict__ W1,   // (8,1024)
            const float* __restrict__ b1,   // (1024)
            const float* __restrict__ W2,   // (1024,128)
            const float* __restrict__ G,    // (B,E,L)
            float* __restrict__ Pt,         // (B,E) ws
            float* __restrict__ s,          // (B,L) ws
            float* __restrict__ tm)         // (B,L) ws
{
    const int b = blockIdx.x;
    const int tid = threadIdx.x;
    __shared__ float hg[CC];
    __shared__ float part[16][EE];
    __shared__ float sg[2];
    __shared__ int   si[2];

    // hgate = gelu(x2 @ W1 + b1): one c per thread
    {
        const int c = tid;
        float acc = b1[c];
#pragma unroll
        for (int t = 0; t < TASKS; ++t) acc += x2[b * TASKS + t] * W1[t * CC + c];
        hg[c] = gelu_exact(acc);
    }
    __syncthreads();

    // logits[e] = sum_c hg[c] * W2[c,e]
    // wave w handles c = w, w+16, ..., lane = e -> coalesced 256B wave loads
    const int wave = tid >> 6;
    const int lane = tid & 63;
    {
        float acc = 0.f;
#pragma unroll
        for (int i = 0; i < 64; ++i) {
            const int c = wave + (i << 4);
            acc += hg[c] * W2[c * 128 + lane];
        }
        part[wave][lane] = acc;
    }
    __syncthreads();

    // wave 0 (64 lanes == 64 experts): cross-wave reduce, softmax, top-2
    if (tid < EE) {
        float v = 0.f;
#pragma unroll
        for (int w = 0; w < 16; ++w) v += part[w][tid];

        float m = v;
#pragma unroll
        for (int off = 32; off; off >>= 1) m = fmaxf(m, __shfl_xor(m, off));
        float ex = expf(v - m);
        float sum = ex;
#pragma unroll
        for (int off = 32; off; off >>= 1) sum += __shfl_xor(sum, off);
        float p = ex / sum + 1e-4f;

        // argmax #1 (ties -> lowest index, matching lax.top_k)
        float bv = p; int bi = tid;
#pragma unroll
        for (int off = 32; off; off >>= 1) {
            float ov = __shfl_xor(bv, off);
            int   oi = __shfl_xor(bi, off);
            if (ov > bv || (ov == bv && oi < bi)) { bv = ov; bi = oi; }
        }
        // argmax #2 (exclude winner lane; p > 0 so -1 acts as -inf)
        float p2 = (tid == bi) ? -1.f : p;
        float bv2 = p2; int bi2 = tid;
#pragma unroll
        for (int off = 32; off; off >>= 1) {
            float ov = __shfl_xor(bv2, off);
            int   oi = __shfl_xor(bi2, off);
            if (ov > bv2 || (ov == bv2 && oi < bi2)) { bv2 = ov; bi2 = oi; }
        }
        Pt[b * EE + tid] = (p >= bv2) ? p : 0.f;
        if (tid == 0) {
            sg[0] = bv;  sg[1] = bv2;
            si[0] = bi;  si[1] = bi2;
        }
    }
    __syncthreads();

    // fused s/tm rows: s[b,l] = g1*G[b,i1,l] + g2*G[b,i2,l]; tm = G1+G2
    {
        const float g1 = sg[0], g2 = sg[1];
        const int i1 = si[0], i2 = si[1];
        const float* G1 = G + ((size_t)b * EE + i1) * LL;
        const float* G2 = G + ((size_t)b * EE + i2) * LL;
        const int l = tid;
        const float a = G1[l];
        const float c = G2[l];
        s[b * LL + l]  = g1 * a + g2 * c;
        tm[b * LL + l] = a + c;
    }
}

// Deterministic reductions: expert_mask (64) and token_mask (1024)
__global__ void reduce_kernel(const float* __restrict__ Pt,  // (B,E)
                              const float* __restrict__ tm,  // (B,L)
                              float* __restrict__ expert_mask,
                              float* __restrict__ token_mask)
{
    const int tid = threadIdx.x;
    if (tid < EE) {
        float acc = 0.f;
        for (int b = 0; b < BB; ++b) acc += Pt[b * EE + tid];
        expert_mask[tid] = acc;
    }
    {
        float acc = 0.f;
        for (int b = 0; b < BB; ++b) acc += tm[b * LL + tid];
        token_mask[tid] = acc;
    }
}

// y[b,l,c] = x[b,l,c] * s[b,l] — the 256 MB streaming kernel
__global__ void scale_kernel(const float4* __restrict__ x,
                             const float*  __restrict__ s,
                             float4* __restrict__ y, int n4)
{
    int i = blockIdx.x * blockDim.x + threadIdx.x;
    const int stride = gridDim.x * blockDim.x;
    for (; i < n4; i += stride) {
        const float sv = __ldg(&s[i >> 8]);   // 256 float4 per (b,l) row
        float4 v = x[i];
        v.x *= sv; v.y *= sv; v.z *= sv; v.w *= sv;
        y[i] = v;
    }
}

extern "C" void kernel_launch(void* const* d_in, const int* in_sizes, int n_in,
                              void* d_out, int out_size, void* d_ws, size_t ws_size,
                              hipStream_t stream) {
    const float* x  = (const float*)d_in[0];  // (32,1024,1024)
    const float* x2 = (const float*)d_in[1];  // (32,8)
    const float* G  = (const float*)d_in[2];  // (32,64,1024)
    const float* W1 = (const float*)d_in[3];  // (8,1024)
    const float* b1 = (const float*)d_in[4];  // (1024)
    const float* W2 = (const float*)d_in[5];  // (1024,128)
    // d_in[6] = k (==2, hardcoded)

    float* y           = (float*)d_out;                  // (32,1024,1024)
    float* expert_mask = y + (size_t)BB * LL * CC;       // (1,64)
    float* token_mask  = expert_mask + EE;               // (1,1024)

    float* s  = (float*)d_ws;        // B*L
    float* tm = s + BB * LL;         // B*L
    float* Pt = tm + BB * LL;        // B*E

    gate_kernel<<<BB, 1024, 0, stream>>>(x2, W1, b1, W2, G, Pt, s, tm);
    reduce_kernel<<<1, 1024, 0, stream>>>(Pt, tm, expert_mask, token_mask);

    const int n4 = BB * LL * CC / 4;
    scale_kernel<<<2048, 256, 0, stream>>>((const float4*)x, s, (float4*)y, n4);
}

// Round 3
// 55.966 us; speedup vs baseline: 2.1432x; 1.0577x over previous
//
#include <hip/hip_runtime.h>
#include <math.h>

#define BB 32
#define LL 1024
#define CC 1024
#define EE 64
#define TASKS 8

typedef float f32x4 __attribute__((ext_vector_type(4)));

__device__ __forceinline__ float gelu_exact(float x) {
    // gelu(x) = 0.5*x*(1+erf(x/sqrt(2))), approximate=False
    return 0.5f * x * (1.0f + erff(x * 0.7071067811865476f));
}

// One block (1024 threads) per batch row:
// hgate -> logits (coalesced, wave-parallel) -> softmax -> top-2 -> P_t
// -> fused s/tm row computation.
__global__ void __launch_bounds__(1024)
gate_kernel(const float* __restrict__ x2,   // (B,8)
            const float* __restrict__ W1,   // (8,1024)
            const float* __restrict__ b1,   // (1024)
            const float* __restrict__ W2,   // (1024,128)
            const float* __restrict__ G,    // (B,E,L)
            float* __restrict__ Pt,         // (B,E) ws
            float* __restrict__ s,          // (B,L) ws
            float* __restrict__ tm)         // (B,L) ws
{
    const int b = blockIdx.x;
    const int tid = threadIdx.x;
    __shared__ float hg[CC];
    __shared__ float part[16][EE];
    __shared__ float sg[2];
    __shared__ int   si[2];

    // hgate = gelu(x2 @ W1 + b1): one c per thread
    {
        const int c = tid;
        float acc = b1[c];
#pragma unroll
        for (int t = 0; t < TASKS; ++t) acc += x2[b * TASKS + t] * W1[t * CC + c];
        hg[c] = gelu_exact(acc);
    }
    __syncthreads();

    // logits[e] = sum_c hg[c] * W2[c,e]
    // wave w handles c = w, w+16, ..., lane = e -> coalesced 256B wave loads
    const int wave = tid >> 6;
    const int lane = tid & 63;
    {
        float acc = 0.f;
#pragma unroll
        for (int i = 0; i < 64; ++i) {
            const int c = wave + (i << 4);
            acc += hg[c] * W2[c * 128 + lane];
        }
        part[wave][lane] = acc;
    }
    __syncthreads();

    // wave 0 (64 lanes == 64 experts): cross-wave reduce, softmax, top-2
    if (tid < EE) {
        float v = 0.f;
#pragma unroll
        for (int w = 0; w < 16; ++w) v += part[w][tid];

        float m = v;
#pragma unroll
        for (int off = 32; off; off >>= 1) m = fmaxf(m, __shfl_xor(m, off));
        float ex = expf(v - m);
        float sum = ex;
#pragma unroll
        for (int off = 32; off; off >>= 1) sum += __shfl_xor(sum, off);
        float p = ex / sum + 1e-4f;

        // argmax #1 (ties -> lowest index, matching lax.top_k)
        float bv = p; int bi = tid;
#pragma unroll
        for (int off = 32; off; off >>= 1) {
            float ov = __shfl_xor(bv, off);
            int   oi = __shfl_xor(bi, off);
            if (ov > bv || (ov == bv && oi < bi)) { bv = ov; bi = oi; }
        }
        // argmax #2 (exclude winner lane; p > 0 so -1 acts as -inf)
        float p2 = (tid == bi) ? -1.f : p;
        float bv2 = p2; int bi2 = tid;
#pragma unroll
        for (int off = 32; off; off >>= 1) {
            float ov = __shfl_xor(bv2, off);
            int   oi = __shfl_xor(bi2, off);
            if (ov > bv2 || (ov == bv2 && oi < bi2)) { bv2 = ov; bi2 = oi; }
        }
        Pt[b * EE + tid] = (p >= bv2) ? p : 0.f;
        if (tid == 0) {
            sg[0] = bv;  sg[1] = bv2;
            si[0] = bi;  si[1] = bi2;
        }
    }
    __syncthreads();

    // fused s/tm rows: s[b,l] = g1*G[b,i1,l] + g2*G[b,i2,l]; tm = G1+G2
    {
        const float g1 = sg[0], g2 = sg[1];
        const int i1 = si[0], i2 = si[1];
        const float* G1 = G + ((size_t)b * EE + i1) * LL;
        const float* G2 = G + ((size_t)b * EE + i2) * LL;
        const int l = tid;
        const float a = G1[l];
        const float c = G2[l];
        s[b * LL + l]  = g1 * a + g2 * c;
        tm[b * LL + l] = a + c;
    }
}

// Deterministic reductions: expert_mask (64) and token_mask (1024)
__global__ void reduce_kernel(const float* __restrict__ Pt,  // (B,E)
                              const float* __restrict__ tm,  // (B,L)
                              float* __restrict__ expert_mask,
                              float* __restrict__ token_mask)
{
    const int tid = threadIdx.x;
    if (tid < EE) {
        float acc = 0.f;
        for (int b = 0; b < BB; ++b) acc += Pt[b * EE + tid];
        expert_mask[tid] = acc;
    }
    {
        float acc = 0.f;
        for (int b = 0; b < BB; ++b) acc += tm[b * LL + tid];
        token_mask[tid] = acc;
    }
}

// y[b,l,c] = x[b,l,c] * s[b,l] — the 256 MB streaming kernel.
// Non-temporal stores keep x L3-resident across replays; unroll-4 gives
// 4 independent load pairs in flight per thread.
__global__ void __launch_bounds__(256)
scale_kernel(const f32x4* __restrict__ x,
             const float* __restrict__ s,
             f32x4* __restrict__ y, int n4)
{
    const int T = gridDim.x * blockDim.x;
    int i = blockIdx.x * blockDim.x + threadIdx.x;
    for (; i + 3 * T < n4; i += 4 * T) {
        const int i0 = i, i1 = i + T, i2 = i + 2 * T, i3 = i + 3 * T;
        f32x4 v0 = x[i0];
        f32x4 v1 = x[i1];
        f32x4 v2 = x[i2];
        f32x4 v3 = x[i3];
        const float s0 = s[i0 >> 8];
        const float s1 = s[i1 >> 8];
        const float s2 = s[i2 >> 8];
        const float s3 = s[i3 >> 8];
        v0 *= s0; v1 *= s1; v2 *= s2; v3 *= s3;
        __builtin_nontemporal_store(v0, &y[i0]);
        __builtin_nontemporal_store(v1, &y[i1]);
        __builtin_nontemporal_store(v2, &y[i2]);
        __builtin_nontemporal_store(v3, &y[i3]);
    }
    for (; i < n4; i += T) {   // tail (unused for this shape)
        f32x4 v = x[i];
        v *= s[i >> 8];
        __builtin_nontemporal_store(v, &y[i]);
    }
}

extern "C" void kernel_launch(void* const* d_in, const int* in_sizes, int n_in,
                              void* d_out, int out_size, void* d_ws, size_t ws_size,
                              hipStream_t stream) {
    const float* x  = (const float*)d_in[0];  // (32,1024,1024)
    const float* x2 = (const float*)d_in[1];  // (32,8)
    const float* G  = (const float*)d_in[2];  // (32,64,1024)
    const float* W1 = (const float*)d_in[3];  // (8,1024)
    const float* b1 = (const float*)d_in[4];  // (1024)
    const float* W2 = (const float*)d_in[5];  // (1024,128)
    // d_in[6] = k (==2, hardcoded)

    float* y           = (float*)d_out;                  // (32,1024,1024)
    float* expert_mask = y + (size_t)BB * LL * CC;       // (1,64)
    float* token_mask  = expert_mask + EE;               // (1,1024)

    float* s  = (float*)d_ws;        // B*L
    float* tm = s + BB * LL;         // B*L
    float* Pt = tm + BB * LL;        // B*E

    gate_kernel<<<BB, 1024, 0, stream>>>(x2, W1, b1, W2, G, Pt, s, tm);
    reduce_kernel<<<1, 1024, 0, stream>>>(Pt, tm, expert_mask, token_mask);

    const int n4 = BB * LL * CC / 4;
    scale_kernel<<<2048, 256, 0, stream>>>((const f32x4*)x, s, (f32x4*)y, n4);
}